// Round 11
// baseline (201.346 us; speedup 1.0000x reference)
//
#include <hip/hip_runtime.h>
#include <cstdint>
#include <cstddef>

#define EPSV 1e-5f
constexpr int B_ = 8;
constexpr int C_ = 512;
constexpr int N_ = 2048;

typedef _Float16 f16x8 __attribute__((ext_vector_type(8)));
typedef float    f32x4 __attribute__((ext_vector_type(4)));

__device__ __forceinline__ unsigned short f16b(float f) {
    _Float16 h = (_Float16)f;
    return __builtin_bit_cast(unsigned short, h);
}

__device__ __forceinline__ void gload_lds16(const void* g, void* l) {
    __builtin_amdgcn_global_load_lds(
        (const __attribute__((address_space(1))) void*)g,
        (__attribute__((address_space(3))) void*)l, 16, 0, 0);
}

// ---------------------------------------------------------------------------
// x (B,C,N) fp32 -> xT (B,N,C) fp16
// ---------------------------------------------------------------------------
__global__ __launch_bounds__(256) void split_x_kernel(
    const float* __restrict__ x, unsigned short* __restrict__ xh)
{
    __shared__ float T[64][65];
    const int b = blockIdx.z, c0 = blockIdx.y * 64, n0 = blockIdx.x * 64;
    const float* xb = x + ((size_t)b * C_ + c0) * N_ + n0;
    const int tid = threadIdx.x;
    const int lr = tid >> 4;
    const int lcn = (tid & 15) * 4;
#pragma unroll
    for (int it = 0; it < 4; ++it) {
        float4 v = *(const float4*)&xb[(size_t)(lr + 16 * it) * N_ + lcn];
        T[lr + 16 * it][lcn + 0] = v.x;
        T[lr + 16 * it][lcn + 1] = v.y;
        T[lr + 16 * it][lcn + 2] = v.z;
        T[lr + 16 * it][lcn + 3] = v.w;
    }
    __syncthreads();
    const int n = tid >> 2, cb = (tid & 3) * 16;
    alignas(16) unsigned short h[16];
#pragma unroll
    for (int i = 0; i < 16; ++i)
        h[i] = f16b(T[cb + i][n]);
    const size_t o = ((size_t)b * N_ + n0 + n) * C_ + c0 + cb;
    *(uint4*)&xh[o]     = *(uint4*)&h[0];
    *(uint4*)&xh[o + 8] = *(uint4*)&h[8];
}

__global__ __launch_bounds__(256) void split_w_kernel(
    const float* __restrict__ W, unsigned short* __restrict__ wh)
{
    const int i = (blockIdx.x * 256 + threadIdx.x) * 4;
    float4 v = *(const float4*)&W[i];
    alignas(8) unsigned short h[4];
    h[0] = f16b(v.x); h[1] = f16b(v.y); h[2] = f16b(v.z); h[3] = f16b(v.w);
    *(ushort4*)&wh[i] = *(ushort4*)&h[0];
}

__global__ __launch_bounds__(512) void param_concat_kernel(
    const float* gq, const float* bq, const float* mq, const float* vq,
    const float* gk, const float* bk, const float* mk, const float* vk,
    float* sg, float* sb, float* sm, float* sv)
{
    const int i = threadIdx.x;
    sg[i] = gq[i];       sg[512 + i] = gk[i];
    sb[i] = bq[i];       sb[512 + i] = bk[i];
    sm[i] = mq[i];       sm[512 + i] = mk[i];
    sv[i] = vq[i];       sv[512 + i] = vk[i];
}

// ---------------------------------------------------------------------------
// 128x128 m97 GEMM — PROJV only.
// ---------------------------------------------------------------------------
__global__ __launch_bounds__(256) void projv_mfma(
    const unsigned short* __restrict__ Ah, const unsigned short* __restrict__ Bh,
    int M, int N, int K, int lda, int ldb,
    long strideA, long strideB, long strideC,
    void* __restrict__ C0,
    const float* __restrict__ g, const float* __restrict__ bt,
    const float* __restrict__ mu, const float* __restrict__ var)
{
    __shared__ char smem[16384];

    const int id = blockIdx.x;
    const int bz = id & 7;
    const int s  = id >> 3;
    const int bx = s & 3, by = s >> 2;
    const int n0 = bx * 128;
    const int m0 = by * 128;

    const unsigned short* Ahb = Ah + (size_t)bz * strideA;
    const unsigned short* Bhb = Bh + (size_t)bz * strideB;

    const int tid = threadIdx.x;
    const int lane = tid & 63;
    const int wv = tid >> 6;
    const int wr = wv >> 1, wc = wv & 1;
    const int l4 = lane >> 4, l15 = lane & 15;
    const int srow = lane >> 2, scol8 = (lane & 3) * 8;

    f32x4 acc[4][4] = {};

    for (int k0 = 0; k0 < K; k0 += 32) {
#pragma unroll
        for (int cc = 0; cc < 2; ++cc) {
            const int c = wv * 2 + cc;
            const size_t aoff = (size_t)(m0 + c * 16 + srow) * lda + k0 + scol8;
            const size_t boff = (size_t)(n0 + c * 16 + srow) * ldb + k0 + scol8;
            gload_lds16(Ahb + aoff, smem + c * 1024);
            gload_lds16(Bhb + boff, smem + 8192 + c * 1024);
        }
        __syncthreads();

        f16x8 ah[4], bh[4];
#pragma unroll
        for (int f = 0; f < 4; ++f) {
            const int arow = wr * 64 + f * 16 + l15;
            const int brow = wc * 64 + f * 16 + l15;
            ah[f] = *(const f16x8*)(smem + arow * 64 + l4 * 16);
            bh[f] = *(const f16x8*)(smem + 8192 + brow * 64 + l4 * 16);
        }
#pragma unroll
        for (int fm = 0; fm < 4; ++fm)
#pragma unroll
            for (int fn = 0; fn < 4; ++fn)
                acc[fm][fn] = __builtin_amdgcn_mfma_f32_16x16x32_f16(
                    ah[fm], bh[fn], acc[fm][fn], 0, 0, 0);
        __syncthreads();
    }

#pragma unroll
    for (int fm = 0; fm < 4; ++fm) {
#pragma unroll
        for (int fn = 0; fn < 4; ++fn) {
            const int m = m0 + wr * 64 + fm * 16 + l4 * 4;
            const int n = n0 + wc * 64 + fn * 16 + l15;
            unsigned short* H = (unsigned short*)C0 + (size_t)bz * strideC;
            const float sc = g[n] * rsqrtf(var[n] + EPSV);
            const float sh = bt[n] - mu[n] * sc;
            alignas(8) unsigned short h4[4];
#pragma unroll
            for (int r = 0; r < 4; ++r)
                h4[r] = f16b(acc[fm][fn][r] * sc + sh);
            *(ushort4*)&H[(size_t)n * M + m] = *(ushort4*)&h4[0];
        }
    }
}

// ---------------------------------------------------------------------------
// Shared phase boilerplate (T3/T4/T5): barrier -> lgkmcnt(0)+sched_barrier ->
// setprio(1) MFMA setprio(0) -> barrier.
// ---------------------------------------------------------------------------
#define BAR_PRE()                                                             \
    __builtin_amdgcn_s_barrier();                                             \
    asm volatile("s_waitcnt lgkmcnt(0)" ::: "memory");                        \
    __builtin_amdgcn_sched_barrier(0);                                        \
    __builtin_amdgcn_s_setprio(1)
#define BAR_POST()                                                            \
    __builtin_amdgcn_s_setprio(0);                                            \
    __builtin_amdgcn_s_barrier()

// ---------------------------------------------------------------------------
// qk256<EPI>: 256x256, BK=64, 8 waves (2Mx4N), 4-phase/K-tile schedule with
// K-split half-tiles (A-K0 | B-K0 | A-K1 | B-K1, each contiguous 16 KiB),
// issue distance 5 phases, vmcnt(6) at q1/q3 (counted, never 0 mid-loop).
// LDS: 2 x 64 KiB buffers.  Swizzle: logical colgrp g stored at g^(row&3);
// staged via pre-swizzled global source (rule #21).
// ---------------------------------------------------------------------------
constexpr int EPI_QK = 0, EPI_PROJT = 2;

template <int EPI>
__global__ __launch_bounds__(512, 2) void qk256(
    const unsigned short* __restrict__ Ah, const unsigned short* __restrict__ Bh,
    int M, int N, int K, int lda, int ldb,
    long strideA, long strideB, long strideC,
    void* __restrict__ C0, float* __restrict__ ML,
    const float* __restrict__ g, const float* __restrict__ bt,
    const float* __restrict__ mu, const float* __restrict__ var)
{
    __shared__ char smem[131072];

    const int id = blockIdx.x;
    const int bz = id & 7;
    const int s  = id >> 3;
    const int bx = s & 7, by = s >> 3;
    const int n0 = bx * 256;
    const int m0 = by * 256;

    const unsigned short* Ahb = Ah + (size_t)bz * strideA;
    const unsigned short* Bhb = Bh + (size_t)bz * strideB;

    const int tid  = threadIdx.x;
    const int lane = tid & 63;
    const int wv   = tid >> 6;
    const int wr   = wv >> 2, wc = wv & 3;
    const int WRB  = wr * 128, WCB = wc * 64;
    const int l4 = lane >> 4, l15 = lane & 15;

    const int NT = K / 64;

    // halftile s: tile T=s>>2, j=s&3: {0:A-K0, 1:B-K0, 2:A-K1, 3:B-K1}
#define ISSUE_Q(sv_)                                                          \
    if ((sv_) < 4 * NT) {                                                     \
        const int T__ = (sv_) >> 2, j__ = (sv_) & 3;                          \
        char* rb = smem + (T__ & 1) * 65536 + ((j__ & 1) ? 32768 : 0) +       \
                   ((j__ >> 1) * 16384);                                      \
        const unsigned short* src = (j__ & 1) ? Bhb : Ahb;                    \
        const int base0 = (j__ & 1) ? n0 : m0;                                \
        const int ld = (j__ & 1) ? ldb : lda;                                 \
        const int colb = T__ * 64 + (j__ >> 1) * 32;                          \
        _Pragma("unroll")                                                     \
        for (int u = 0; u < 2; ++u) {                                         \
            const int L = u * 512 + tid;                                      \
            const int row = L >> 2;                                           \
            gload_lds16(src + (size_t)(base0 + row) * ld + colb +             \
                            (((tid & 3) ^ (row & 3)) * 8),                    \
                        rb + L * 16);                                         \
        }                                                                     \
    }

#define RDA(kk, dst)                                                          \
    _Pragma("unroll")                                                         \
    for (int m_ = 0; m_ < 8; ++m_) {                                          \
        const int r_ = WRB + m_ * 16 + l15;                                   \
        dst[m_] = *(const f16x8*)(cur + (kk) * 16384 + r_ * 64 +              \
                                  ((l4 ^ (r_ & 3)) * 16));                    \
    }
#define RDB(kk, nlo, dst)                                                     \
    _Pragma("unroll")                                                         \
    for (int n_ = 0; n_ < 2; ++n_) {                                          \
        const int r_ = WCB + ((nlo) + n_) * 16 + l15;                         \
        dst[n_] = *(const f16x8*)(cur + 32768 + (kk) * 16384 + r_ * 64 +      \
                                  ((l4 ^ (r_ & 3)) * 16));                    \
    }
#define MFM(nlo)                                                              \
    _Pragma("unroll")                                                         \
    for (int m_ = 0; m_ < 8; ++m_)                                            \
        _Pragma("unroll")                                                     \
        for (int n_ = 0; n_ < 2; ++n_)                                        \
            acc[m_][(nlo) + n_] = __builtin_amdgcn_mfma_f32_16x16x32_f16(     \
                ah[m_], bq[n_], acc[m_][(nlo) + n_], 0, 0, 0);

    f32x4 acc[8][4] = {};
    f16x8 ah[8], bq[2];

    // prologue: tile0 (s0..3) + tile1 A-K0 (s4); need s0,s1 before q0
    ISSUE_Q(0); ISSUE_Q(1); ISSUE_Q(2); ISSUE_Q(3); ISSUE_Q(4);
    asm volatile("s_waitcnt vmcnt(6)" ::: "memory");
    __builtin_amdgcn_s_barrier();

    for (int t = 0; t < NT; ++t) {
        char* cur = smem + (t & 1) * 65536;
        // q0: kk0, n0-1
        RDA(0, ah); RDB(0, 0, bq);
        ISSUE_Q(4 * t + 5);
        BAR_PRE(); MFM(0); BAR_POST();
        // q1: kk0, n2-3
        RDB(0, 2, bq);
        ISSUE_Q(4 * t + 6);
        if (t + 1 < NT) { asm volatile("s_waitcnt vmcnt(6)" ::: "memory"); }
        else            { asm volatile("s_waitcnt vmcnt(0)" ::: "memory"); }
        BAR_PRE(); MFM(2); BAR_POST();
        // q2: kk1, n0-1
        RDA(1, ah); RDB(1, 0, bq);
        ISSUE_Q(4 * t + 7);
        BAR_PRE(); MFM(0); BAR_POST();
        // q3: kk1, n2-3
        RDB(1, 2, bq);
        ISSUE_Q(4 * t + 8);
        if (t + 2 < NT)       { asm volatile("s_waitcnt vmcnt(6)" ::: "memory"); }
        else if (t + 2 == NT) { asm volatile("s_waitcnt vmcnt(4)" ::: "memory"); }
        BAR_PRE(); MFM(2); BAR_POST();
    }
#undef ISSUE_Q
#undef RDA
#undef RDB
#undef MFM

    if constexpr (EPI == EPI_QK) {
        unsigned short* H = (unsigned short*)C0 + (size_t)bz * strideC;
        const int tcol = bx * 4 + wc;
        const size_t mbase = (((size_t)bz * 32 + tcol) * 2) * 2048;
#pragma unroll
        for (int m = 0; m < 8; ++m) {
#pragma unroll
            for (int r = 0; r < 4; ++r) {
                float mx = fmaxf(fmaxf(acc[m][0][r], acc[m][1][r]),
                                 fmaxf(acc[m][2][r], acc[m][3][r]));
#pragma unroll
                for (int off = 1; off < 16; off <<= 1)
                    mx = fmaxf(mx, __shfl_xor(mx, off));
                float pe[4];
                float s2 = 0.f;
#pragma unroll
                for (int n = 0; n < 4; ++n) {
                    pe[n] = __expf(acc[m][n][r] - mx);
                    s2 += pe[n];
                }
#pragma unroll
                for (int off = 1; off < 16; off <<= 1)
                    s2 += __shfl_xor(s2, off);
                const int rloc = WRB + m * 16 + l4 * 4 + r;
                if (l15 == 0) {
                    ML[mbase + m0 + rloc] = mx;
                    ML[mbase + 2048 + m0 + rloc] = s2;
                }
#pragma unroll
                for (int n = 0; n < 4; ++n)
                    H[(size_t)(m0 + rloc) * 2048 + n0 + WCB + n * 16 + l15] =
                        f16b(pe[n]);
            }
        }
    } else {  // EPI_PROJT
        unsigned short* H = (unsigned short*)C0 + (size_t)bz * strideC;
#pragma unroll
        for (int m = 0; m < 8; ++m) {
            const int mg = m0 + WRB + m * 16 + l4 * 4;
            float sc[4], sh[4];
#pragma unroll
            for (int r = 0; r < 4; ++r) {
                const int o = mg + r;
                sc[r] = g[o] * rsqrtf(var[o] + EPSV);
                sh[r] = bt[o] - mu[o] * sc[r];
            }
#pragma unroll
            for (int n = 0; n < 4; ++n) {
                const int ng = n0 + WCB + n * 16 + l15;
                alignas(8) unsigned short h4[4];
#pragma unroll
                for (int r = 0; r < 4; ++r)
                    h4[r] = f16b(acc[m][n][r] * sc[r] + sh[r]);
                *(ushort4*)&H[(size_t)ng * M + mg] = *(ushort4*)&h4[0];
            }
        }
    }
}

// ---------------------------------------------------------------------------
// pv256: 256x128, BK=64, NT=32, 2-phase/K-tile K-split schedule.
// Half-tile unit = {A-Kh (2 loads) + B-Kh (1 load)} = 3 loads/thread.
// LDS: 2 x 48 KiB buffers + 16 KiB corr.  vmcnt(6) counted, (3)/(0) tail.
// ---------------------------------------------------------------------------
__global__ __launch_bounds__(512, 2) void pv256(
    const unsigned short* __restrict__ Ah, const unsigned short* __restrict__ Bh,
    int K, int lda, int ldb, long strideA, long strideB, long strideC,
    void* __restrict__ C0,
    const float* __restrict__ corr, const float* __restrict__ linv)
{
    __shared__ char smem[114688];

    const int id = blockIdx.x;
    const int bz = id & 7;
    const int s  = id >> 3;
    const int bx = s & 3, by = s >> 2;
    const int n0 = bx * 128;
    const int m0 = by * 256;

    const unsigned short* Ahb = Ah + (size_t)bz * strideA;
    const unsigned short* Bhb = Bh + (size_t)bz * strideB;

    const int tid  = threadIdx.x;
    const int lane = tid & 63;
    const int wv   = tid >> 6;
    const int wr   = wv >> 2, wc = wv & 3;
    const int WRB  = wr * 128, WCB = wc * 32;
    const int l4 = lane >> 4, l15 = lane & 15;

    const int NT = K / 64;

    unsigned short* corrLds = (unsigned short*)(smem + 98304);
    for (int idx = tid; idx < 2048; idx += 512) {
        const int t = idx >> 6, i4 = (idx & 63) * 4;
        float4 c4 = *(const float4*)&corr[((size_t)bz * 32 + t) * 2048 + m0 + i4];
        alignas(8) unsigned short h4[4] =
            {f16b(c4.x), f16b(c4.y), f16b(c4.z), f16b(c4.w)};
        *(ushort4*)&corrLds[(size_t)t * 256 + i4] = *(ushort4*)&h4[0];
    }
    __syncthreads();

    // unit s: tile T=s>>1, h=s&1: A-Kh (16 KiB) + B-Kh (8 KiB)
#define ISSUE_P(sv_)                                                          \
    if ((sv_) < 2 * NT) {                                                     \
        const int T__ = (sv_) >> 1, h__ = (sv_) & 1;                          \
        char* rb = smem + (T__ & 1) * 49152;                                  \
        const int colb = T__ * 64 + h__ * 32;                                 \
        _Pragma("unroll")                                                     \
        for (int u = 0; u < 2; ++u) {                                         \
            const int L = u * 512 + tid;                                      \
            const int row = L >> 2;                                           \
            gload_lds16(Ahb + (size_t)(m0 + row) * lda + colb +               \
                            (((tid & 3) ^ (row & 3)) * 8),                    \
                        rb + h__ * 16384 + L * 16);                           \
        }                                                                     \
        {                                                                     \
            const int row = tid >> 2;                                         \
            gload_lds16(Bhb + (size_t)(n0 + row) * ldb + colb +               \
                            (((tid & 3) ^ (row & 3)) * 8),                    \
                        rb + 32768 + h__ * 8192 + tid * 16);                  \
        }                                                                     \
    }

#define RDAP(kk)                                                              \
    _Pragma("unroll")                                                         \
    for (int m_ = 0; m_ < 8; ++m_) {                                          \
        const int r_ = WRB + m_ * 16 + l15;                                   \
        ah[m_] = *(const f16x8*)(cur + (kk) * 16384 + r_ * 64 +               \
                                 ((l4 ^ (r_ & 3)) * 16));                     \
    }
#define RDBP(kk)                                                              \
    _Pragma("unroll")                                                         \
    for (int n_ = 0; n_ < 2; ++n_) {                                          \
        const int r_ = WCB + n_ * 16 + l15;                                   \
        bq[n_] = *(const f16x8*)(cur + 32768 + (kk) * 8192 + r_ * 64 +        \
                                 ((l4 ^ (r_ & 3)) * 16));                     \
    }
#define CORRM(t)                                                              \
    _Pragma("unroll")                                                         \
    for (int m_ = 0; m_ < 8; ++m_) {                                          \
        const _Float16 cf = ((const _Float16*)corrLds)                        \
            [(size_t)(t) * 256 + WRB + m_ * 16 + l15];                        \
        ah[m_] = ah[m_] * cf;                                                 \
    }
#define MFMP()                                                                \
    _Pragma("unroll")                                                         \
    for (int m_ = 0; m_ < 8; ++m_)                                            \
        _Pragma("unroll")                                                     \
        for (int n_ = 0; n_ < 2; ++n_)                                        \
            acc[m_][n_] = __builtin_amdgcn_mfma_f32_16x16x32_f16(             \
                ah[m_], bq[n_], acc[m_][n_], 0, 0, 0);

    f32x4 acc[8][2] = {};
    f16x8 ah[8], bq[2];

    ISSUE_P(0); ISSUE_P(1); ISSUE_P(2);
    asm volatile("s_waitcnt vmcnt(6)" ::: "memory");
    __builtin_amdgcn_s_barrier();

    for (int t = 0; t < NT; ++t) {
        char* cur = smem + (t & 1) * 49152;
        // q0: kk0
        RDAP(0); RDBP(0); CORRM(t);
        ISSUE_P(2 * t + 3);
        if (t + 1 < NT) { asm volatile("s_waitcnt vmcnt(6)" ::: "memory"); }
        else            { asm volatile("s_waitcnt vmcnt(0)" ::: "memory"); }
        BAR_PRE(); MFMP(); BAR_POST();
        // q1: kk1
        RDAP(1); RDBP(1); CORRM(t);
        ISSUE_P(2 * t + 4);
        if (t + 2 < NT)       { asm volatile("s_waitcnt vmcnt(6)" ::: "memory"); }
        else if (t + 2 == NT) { asm volatile("s_waitcnt vmcnt(3)" ::: "memory"); }
        BAR_PRE(); MFMP(); BAR_POST();
    }
#undef ISSUE_P
#undef RDAP
#undef RDBP
#undef CORRM
#undef MFMP

    float* Cb = (float*)C0 + (size_t)bz * strideC;
    const float* lb = linv + (size_t)bz * 2048;
#pragma unroll
    for (int m = 0; m < 8; ++m) {
        const int mrow = m0 + WRB + m * 16 + l4 * 4;
        float lv[4];
#pragma unroll
        for (int r = 0; r < 4; ++r)
            lv[r] = lb[mrow + r];
#pragma unroll
        for (int n = 0; n < 2; ++n) {
            const int col = n0 + WCB + n * 16 + l15;
            float4 o4 = make_float4(acc[m][n][0] * lv[0],
                                    acc[m][n][1] * lv[1],
                                    acc[m][n][2] * lv[2],
                                    acc[m][n][3] * lv[3]);
            *(float4*)&Cb[(size_t)col * 2048 + mrow] = o4;
        }
    }
}

// ---------------------------------------------------------------------------
__global__ __launch_bounds__(256) void ml_combine_kernel(
    const float* __restrict__ ml, float* __restrict__ corr,
    float* __restrict__ linv)
{
    const int idx = blockIdx.x * 256 + threadIdx.x;
    const int b = idx >> 11, i = idx & 2047;
    const float* base = ml + ((size_t)b * 32) * 2 * 2048 + i;
    float M = -3.0e38f;
#pragma unroll 8
    for (int t = 0; t < 32; ++t)
        M = fmaxf(M, base[(size_t)t * 4096]);
    float L = 0.f;
    float* cb = corr + (size_t)b * 32 * 2048 + i;
#pragma unroll 8
    for (int t = 0; t < 32; ++t) {
        const float c = __expf(base[(size_t)t * 4096] - M);
        L += c * base[(size_t)t * 4096 + 2048];
        cb[(size_t)t * 2048] = c;
    }
    linv[idx] = 1.0f / L;
}

// ---------------------------------------------------------------------------
extern "C" void kernel_launch(void* const* d_in, const int* in_sizes, int n_in,
                              void* d_out, int out_size, void* d_ws, size_t ws_size,
                              hipStream_t stream)
{
    (void)in_sizes; (void)n_in; (void)out_size; (void)ws_size;
    const float* x  = (const float*)d_in[0];
    const float* Wq = (const float*)d_in[1];
    const float* gq = (const float*)d_in[2];
    const float* bq = (const float*)d_in[3];
    const float* mq = (const float*)d_in[4];
    const float* vq = (const float*)d_in[5];
    const float* Wk = (const float*)d_in[6];
    const float* gk = (const float*)d_in[7];
    const float* bk = (const float*)d_in[8];
    const float* mk = (const float*)d_in[9];
    const float* vk = (const float*)d_in[10];
    const float* Wv = (const float*)d_in[11];
    const float* gv = (const float*)d_in[12];
    const float* bv = (const float*)d_in[13];
    const float* mv = (const float*)d_in[14];
    const float* vv = (const float*)d_in[15];
    float* out = (float*)d_out;

    const size_t MiB = 1048576;
    char* ws = (char*)d_ws;
    unsigned short* Wqh = (unsigned short*)(ws + 0 * 524288);
    unsigned short* Wkh = (unsigned short*)(ws + 1 * 524288);
    unsigned short* Wvh = (unsigned short*)(ws + 2 * 524288);
    unsigned short* vbf  = (unsigned short*)(ws + 2 * MiB);
    unsigned short* qkTh = (unsigned short*)(ws + 18 * MiB);
    unsigned short* xTh  = (unsigned short*)(ws + 50 * MiB);
    unsigned short* pbuf = (unsigned short*)(ws + 66 * MiB);
    float* mlbuf = (float*)(ws + 130 * MiB);
    float* corr  = (float*)(ws + 134 * MiB);
    float* linv  = (float*)(ws + 136 * MiB);
    float* sg = (float*)(ws + 136 * MiB + 65536);
    float* sb = sg + 1024;
    float* sm = sb + 1024;
    float* sv = sm + 1024;

    const long BS = (long)N_ * C_;
    const long QKS = (long)N_ * 1024;

    split_x_kernel<<<dim3(N_ / 64, C_ / 64, B_), 256, 0, stream>>>(x, xTh);
    split_w_kernel<<<dim3(256), 256, 0, stream>>>(Wq, Wqh);
    split_w_kernel<<<dim3(256), 256, 0, stream>>>(Wk, Wkh);
    split_w_kernel<<<dim3(256), 256, 0, stream>>>(Wv, Wvh);
    param_concat_kernel<<<dim3(1), 512, 0, stream>>>(
        gq, bq, mq, vq, gk, bk, mk, vk, sg, sb, sm, sv);

    // stacked q/k projection (M=1024)
    qk256<EPI_PROJT><<<dim3(256), 512, 0, stream>>>(
        Wqh, xTh, 1024, 2048, 512, 512, 512, 0, BS, QKS, qkTh,
        nullptr, sg, sb, sm, sv);

    projv_mfma<<<dim3(512), 256, 0, stream>>>(
        xTh, Wvh, 2048, 512, 512, 512, 512, BS, 0, BS, vbf,
        gv, bv, mv, vv);

    // logits -> p_local + stats
    qk256<EPI_QK><<<dim3(512), 512, 0, stream>>>(
        qkTh, qkTh + 512, 2048, 2048, 512, 1024, 1024, QKS, QKS,
        (long)N_ * N_, pbuf, mlbuf, nullptr, nullptr, nullptr, nullptr);

    ml_combine_kernel<<<dim3(B_ * N_ / 256), 256, 0, stream>>>(
        mlbuf, corr, linv);

    pv256<<<dim3(256), 512, 0, stream>>>(
        pbuf, vbf, 2048, 2048, 2048, (long)N_ * N_, BS, BS, out, corr, linv);
}

// Round 12
// 176.912 us; speedup vs baseline: 1.1381x; 1.1381x over previous
//
#include <hip/hip_runtime.h>
#include <cstdint>
#include <cstddef>

#define EPSV 1e-5f
constexpr int B_ = 8;
constexpr int C_ = 512;
constexpr int N_ = 2048;

typedef _Float16 f16x8 __attribute__((ext_vector_type(8)));
typedef float    f32x4 __attribute__((ext_vector_type(4)));

__device__ __forceinline__ unsigned short f16b(float f) {
    _Float16 h = (_Float16)f;
    return __builtin_bit_cast(unsigned short, h);
}

__device__ __forceinline__ void gload_lds16(const void* g, void* l) {
    __builtin_amdgcn_global_load_lds(
        (const __attribute__((address_space(1))) void*)g,
        (__attribute__((address_space(3))) void*)l, 16, 0, 0);
}

// ---------------------------------------------------------------------------
// x (B,C,N) fp32 -> xT (B,N,C) fp16
// ---------------------------------------------------------------------------
__global__ __launch_bounds__(256) void split_x_kernel(
    const float* __restrict__ x, unsigned short* __restrict__ xh)
{
    __shared__ float T[64][65];
    const int b = blockIdx.z, c0 = blockIdx.y * 64, n0 = blockIdx.x * 64;
    const float* xb = x + ((size_t)b * C_ + c0) * N_ + n0;
    const int tid = threadIdx.x;
    const int lr = tid >> 4;
    const int lcn = (tid & 15) * 4;
#pragma unroll
    for (int it = 0; it < 4; ++it) {
        float4 v = *(const float4*)&xb[(size_t)(lr + 16 * it) * N_ + lcn];
        T[lr + 16 * it][lcn + 0] = v.x;
        T[lr + 16 * it][lcn + 1] = v.y;
        T[lr + 16 * it][lcn + 2] = v.z;
        T[lr + 16 * it][lcn + 3] = v.w;
    }
    __syncthreads();
    const int n = tid >> 2, cb = (tid & 3) * 16;
    alignas(16) unsigned short h[16];
#pragma unroll
    for (int i = 0; i < 16; ++i)
        h[i] = f16b(T[cb + i][n]);
    const size_t o = ((size_t)b * N_ + n0 + n) * C_ + c0 + cb;
    *(uint4*)&xh[o]     = *(uint4*)&h[0];
    *(uint4*)&xh[o + 8] = *(uint4*)&h[8];
}

__global__ __launch_bounds__(256) void split_w_kernel(
    const float* __restrict__ W, unsigned short* __restrict__ wh)
{
    const int i = (blockIdx.x * 256 + threadIdx.x) * 4;
    float4 v = *(const float4*)&W[i];
    alignas(8) unsigned short h[4];
    h[0] = f16b(v.x); h[1] = f16b(v.y); h[2] = f16b(v.z); h[3] = f16b(v.w);
    *(ushort4*)&wh[i] = *(ushort4*)&h[0];
}

// concat BN params of q, k, v into stacked [1536] arrays
__global__ __launch_bounds__(512) void param_concat_kernel(
    const float* gq, const float* bq, const float* mq, const float* vq,
    const float* gk, const float* bk, const float* mk, const float* vk,
    const float* gv, const float* bv, const float* mv, const float* vv,
    float* sg, float* sb, float* sm, float* sv)
{
    const int i = threadIdx.x;
    sg[i] = gq[i];  sg[512 + i] = gk[i];  sg[1024 + i] = gv[i];
    sb[i] = bq[i];  sb[512 + i] = bk[i];  sb[1024 + i] = bv[i];
    sm[i] = mq[i];  sm[512 + i] = mk[i];  sm[1024 + i] = mv[i];
    sv[i] = vq[i];  sv[512 + i] = vk[i];  sv[1024 + i] = vv[i];
}

// ---------------------------------------------------------------------------
// qk256<EPI>: 256x256 tile, BK=64, 8 waves (2Mx4N, per-wave 128x64),
// 128 KiB double-buffered LDS, counted vmcnt(8), T2 XOR swizzle (128B rows,
// slot ^= row&7 involution on stage source and ds_read), setprio cluster.
// EPI_QK:    A=qT B=kT (stacked, lda/ldb=1024); epilogue exp/stats + p fp16.
// EPI_PROJT: A=stacked [Wq|Wk|Wv] (M=1536, strideA=0), B=xT; BN epilogue.
//            by<4  -> q/k section: fp16 out at qkTh[n*1024 + m]
//            by>=4 -> v section:   fp16 out at vbf[(m-1024)*2048 + n]
// ---------------------------------------------------------------------------
constexpr int EPI_QK = 0, EPI_PROJT = 2;

template <int EPI>
__global__ __launch_bounds__(512, 2) void qk256(
    const unsigned short* __restrict__ Ah, const unsigned short* __restrict__ Bh,
    int K, int lda, int ldb,
    long strideA, long strideB, long strideC, long strideC2,
    void* __restrict__ C0, void* __restrict__ C1, float* __restrict__ ML,
    const float* __restrict__ g, const float* __restrict__ bt,
    const float* __restrict__ mu, const float* __restrict__ var)
{
    __shared__ char smem[131072];          // 2 x (32KB A + 32KB B)

    const int id = blockIdx.x;
    const int bz = id & 7;                 // batch-pinned XCD
    const int s  = id >> 3;
    const int bx = s & 7, by = s >> 3;
    const int n0 = bx * 256;
    const int m0 = by * 256;

    const unsigned short* Ahb = Ah + (size_t)bz * strideA;
    const unsigned short* Bhb = Bh + (size_t)bz * strideB;

    const int tid  = threadIdx.x;
    const int lane = tid & 63;
    const int wv   = tid >> 6;
    const int wr   = wv >> 2, wc = wv & 3;
    const int WRB  = wr * 128, WCB = wc * 64;
    const int l4 = lane >> 4, l15 = lane & 15;

    const int srow  = tid >> 3;                       // 0..63
    const int sslot = ((tid & 7) ^ (srow & 7)) * 8;   // pre-swizzled col

#define STAGE(t)                                                              \
    {                                                                         \
        char* dst = smem + ((t) & 1) * 65536;                                 \
        const unsigned short* asrc =                                          \
            Ahb + (size_t)(m0 + srow) * lda + (t) * 64 + sslot;               \
        _Pragma("unroll")                                                     \
        for (int u = 0; u < 4; ++u)                                           \
            gload_lds16(asrc + (size_t)(u * 64) * lda,                        \
                        dst + u * 8192 + tid * 16);                           \
        const unsigned short* bsrc =                                          \
            Bhb + (size_t)(n0 + srow) * ldb + (t) * 64 + sslot;               \
        _Pragma("unroll")                                                     \
        for (int u = 0; u < 4; ++u)                                           \
            gload_lds16(bsrc + (size_t)(u * 64) * ldb,                        \
                        dst + 32768 + u * 8192 + tid * 16);                   \
    }

    f32x4 acc[8][4] = {};
    const int NT = K / 64;

    STAGE(0);

    for (int t = 0; t < NT; ++t) {
        char* cur = smem + (t & 1) * 65536;
        __builtin_amdgcn_s_barrier();          // buf[(t+1)&1] fully consumed
        if (t + 1 < NT) {
            STAGE(t + 1);
            asm volatile("s_waitcnt vmcnt(8)" ::: "memory");
        } else {
            asm volatile("s_waitcnt vmcnt(0)" ::: "memory");
        }
        __builtin_amdgcn_s_barrier();          // tile t staged by all waves

        f16x8 ah[8][2], bh[4][2];
#pragma unroll
        for (int m = 0; m < 8; ++m) {
            const int row = WRB + m * 16 + l15;
#pragma unroll
            for (int kk = 0; kk < 2; ++kk)
                ah[m][kk] = *(const f16x8*)(cur + row * 128 +
                                            (((kk << 2) | l4) ^ (row & 7)) * 16);
        }
#pragma unroll
        for (int n = 0; n < 4; ++n) {
            const int row = WCB + n * 16 + l15;
#pragma unroll
            for (int kk = 0; kk < 2; ++kk)
                bh[n][kk] = *(const f16x8*)(cur + 32768 + row * 128 +
                                            (((kk << 2) | l4) ^ (row & 7)) * 16);
        }
        __builtin_amdgcn_s_setprio(1);
#pragma unroll
        for (int kk = 0; kk < 2; ++kk)
#pragma unroll
            for (int m = 0; m < 8; ++m)
#pragma unroll
                for (int n = 0; n < 4; ++n)
                    acc[m][n] = __builtin_amdgcn_mfma_f32_16x16x32_f16(
                        ah[m][kk], bh[n][kk], acc[m][n], 0, 0, 0);
        __builtin_amdgcn_s_setprio(0);
    }
#undef STAGE

    if constexpr (EPI == EPI_QK) {
        unsigned short* H = (unsigned short*)C0 + (size_t)bz * strideC;
        const int tcol = bx * 4 + wc;                     // 64-col tile id
        const size_t mbase = (((size_t)bz * 32 + tcol) * 2) * 2048;
#pragma unroll
        for (int m = 0; m < 8; ++m) {
#pragma unroll
            for (int r = 0; r < 4; ++r) {
                float mx = fmaxf(fmaxf(acc[m][0][r], acc[m][1][r]),
                                 fmaxf(acc[m][2][r], acc[m][3][r]));
#pragma unroll
                for (int off = 1; off < 16; off <<= 1)
                    mx = fmaxf(mx, __shfl_xor(mx, off));
                float pe[4];
                float s2 = 0.f;
#pragma unroll
                for (int n = 0; n < 4; ++n) {
                    pe[n] = __expf(acc[m][n][r] - mx);
                    s2 += pe[n];
                }
#pragma unroll
                for (int off = 1; off < 16; off <<= 1)
                    s2 += __shfl_xor(s2, off);
                const int rloc = WRB + m * 16 + l4 * 4 + r;   // 0..255
                if (l15 == 0) {
                    ML[mbase + m0 + rloc] = mx;
                    ML[mbase + 2048 + m0 + rloc] = s2;
                }
#pragma unroll
                for (int n = 0; n < 4; ++n)
                    H[(size_t)(m0 + rloc) * 2048 + n0 + WCB + n * 16 + l15] =
                        f16b(pe[n]);
            }
        }
    } else {  // EPI_PROJT: stacked BN by m; section switch is block-uniform
        if (m0 < 1024) {
            unsigned short* H = (unsigned short*)C0 + (size_t)bz * strideC;
#pragma unroll
            for (int m = 0; m < 8; ++m) {
                const int mg = m0 + WRB + m * 16 + l4 * 4;
                float sc[4], sh[4];
#pragma unroll
                for (int r = 0; r < 4; ++r) {
                    const int o = mg + r;
                    sc[r] = g[o] * rsqrtf(var[o] + EPSV);
                    sh[r] = bt[o] - mu[o] * sc[r];
                }
#pragma unroll
                for (int n = 0; n < 4; ++n) {
                    const int ng = n0 + WCB + n * 16 + l15;
                    alignas(8) unsigned short h4[4];
#pragma unroll
                    for (int r = 0; r < 4; ++r)
                        h4[r] = f16b(acc[m][n][r] * sc[r] + sh[r]);
                    *(ushort4*)&H[(size_t)ng * 1024 + mg] = *(ushort4*)&h4[0];
                }
            }
        } else {
            unsigned short* V = (unsigned short*)C1 + (size_t)bz * strideC2;
#pragma unroll
            for (int m = 0; m < 8; ++m) {
                const int mg = m0 + WRB + m * 16 + l4 * 4;
                float sc[4], sh[4];
#pragma unroll
                for (int r = 0; r < 4; ++r) {
                    const int o = mg + r;
                    sc[r] = g[o] * rsqrtf(var[o] + EPSV);
                    sh[r] = bt[o] - mu[o] * sc[r];
                }
                const int d0 = mg - 1024;
#pragma unroll
                for (int n = 0; n < 4; ++n) {
                    const int ng = n0 + WCB + n * 16 + l15;
#pragma unroll
                    for (int r = 0; r < 4; ++r)
                        V[(size_t)(d0 + r) * 2048 + ng] =
                            f16b(acc[m][n][r] * sc[r] + sh[r]);
                }
            }
        }
    }
}

// ---------------------------------------------------------------------------
// PV: 256x128, tri-buffered, counted vmcnt(6) — round-9/10 code verbatim.
// ---------------------------------------------------------------------------
__global__ __launch_bounds__(512, 2) void pv256(
    const unsigned short* __restrict__ Ah, const unsigned short* __restrict__ Bh,
    int K, int lda, int ldb, long strideA, long strideB, long strideC,
    void* __restrict__ C0,
    const float* __restrict__ corr, const float* __restrict__ linv)
{
    constexpr int BUFSZ = 49152;
    __shared__ char smem[163840];

    const int id = blockIdx.x;
    const int bz = id & 7;
    const int s  = id >> 3;
    const int bx = s & 3, by = s >> 2;
    const int n0 = bx * 128;
    const int m0 = by * 256;

    const unsigned short* Ahb = Ah + (size_t)bz * strideA;
    const unsigned short* Bhb = Bh + (size_t)bz * strideB;

    const int tid  = threadIdx.x;
    const int lane = tid & 63;
    const int wv   = tid >> 6;
    const int wr   = wv >> 2, wc = wv & 3;
    const int WRB  = wr * 128, WCB = wc * 32;
    const int l4 = lane >> 4, l15 = lane & 15;

    const int srow = tid >> 3;
    const int sslot = ((tid & 7) ^ (srow & 7)) * 8;

    unsigned short* corrLds = (unsigned short*)(smem + 147456);
    for (int idx = tid; idx < 2048; idx += 512) {
        const int t = idx >> 6, i4 = (idx & 63) * 4;
        float4 c4 = *(const float4*)&corr[((size_t)bz * 32 + t) * 2048 + m0 + i4];
        alignas(8) unsigned short h4[4] =
            {f16b(c4.x), f16b(c4.y), f16b(c4.z), f16b(c4.w)};
        *(ushort4*)&corrLds[(size_t)t * 256 + i4] = *(ushort4*)&h4[0];
    }
    __syncthreads();

#define STAGE(t)                                                              \
    {                                                                         \
        char* dst = smem + ((t) % 3) * BUFSZ;                                 \
        const unsigned short* asrc =                                          \
            Ahb + (size_t)(m0 + srow) * lda + (t) * 64 + sslot;               \
        _Pragma("unroll")                                                     \
        for (int u = 0; u < 4; ++u)                                           \
            gload_lds16(asrc + (size_t)(u * 64) * lda,                        \
                        dst + u * 8192 + tid * 16);                           \
        const unsigned short* bsrc =                                          \
            Bhb + (size_t)(n0 + srow) * ldb + (t) * 64 + sslot;               \
        _Pragma("unroll")                                                     \
        for (int u = 0; u < 2; ++u)                                           \
            gload_lds16(bsrc + (size_t)(u * 64) * ldb,                        \
                        dst + 32768 + u * 8192 + tid * 16);                   \
    }

    f32x4 acc[8][2] = {};
    const int NT = K / 64;

    STAGE(0);
    STAGE(1);

    for (int t = 0; t < NT; ++t) {
        char* cur = smem + (t % 3) * BUFSZ;
        if (t + 2 < NT) {
            asm volatile("s_waitcnt vmcnt(6)" ::: "memory");
        } else {
            asm volatile("s_waitcnt vmcnt(0)" ::: "memory");
        }
        __builtin_amdgcn_s_barrier();
        asm volatile("" ::: "memory");
        if (t + 2 < NT) STAGE(t + 2);

        f16x8 ah[8][2], bh[2][2];
#pragma unroll
        for (int m = 0; m < 8; ++m) {
            const int row = WRB + m * 16 + l15;
#pragma unroll
            for (int kk = 0; kk < 2; ++kk)
                ah[m][kk] = *(const f16x8*)(cur + row * 128 +
                                            (((kk << 2) | l4) ^ (row & 7)) * 16);
        }
#pragma unroll
        for (int n = 0; n < 2; ++n) {
            const int row = WCB + n * 16 + l15;
#pragma unroll
            for (int kk = 0; kk < 2; ++kk)
                bh[n][kk] = *(const f16x8*)(cur + 32768 + row * 128 +
                                            (((kk << 2) | l4) ^ (row & 7)) * 16);
        }
#pragma unroll
        for (int m = 0; m < 8; ++m) {
            const _Float16 cf = ((const _Float16*)corrLds)
                [(size_t)t * 256 + WRB + m * 16 + l15];
            ah[m][0] = ah[m][0] * cf;
            ah[m][1] = ah[m][1] * cf;
        }
        __builtin_amdgcn_s_setprio(1);
#pragma unroll
        for (int kk = 0; kk < 2; ++kk)
#pragma unroll
            for (int m = 0; m < 8; ++m)
#pragma unroll
                for (int n = 0; n < 2; ++n)
                    acc[m][n] = __builtin_amdgcn_mfma_f32_16x16x32_f16(
                        ah[m][kk], bh[n][kk], acc[m][n], 0, 0, 0);
        __builtin_amdgcn_s_setprio(0);
    }
#undef STAGE

    float* Cb = (float*)C0 + (size_t)bz * strideC;
    const float* lb = linv + (size_t)bz * 2048;
#pragma unroll
    for (int m = 0; m < 8; ++m) {
        const int mrow = m0 + WRB + m * 16 + l4 * 4;
        float lv[4];
#pragma unroll
        for (int r = 0; r < 4; ++r)
            lv[r] = lb[mrow + r];
#pragma unroll
        for (int n = 0; n < 2; ++n) {
            const int col = n0 + WCB + n * 16 + l15;
            float4 o4 = make_float4(acc[m][n][0] * lv[0],
                                    acc[m][n][1] * lv[1],
                                    acc[m][n][2] * lv[2],
                                    acc[m][n][3] * lv[3]);
            *(float4*)&Cb[(size_t)col * 2048 + mrow] = o4;
        }
    }
}

// ---------------------------------------------------------------------------
__global__ __launch_bounds__(256) void ml_combine_kernel(
    const float* __restrict__ ml, float* __restrict__ corr,
    float* __restrict__ linv)
{
    const int idx = blockIdx.x * 256 + threadIdx.x;
    const int b = idx >> 11, i = idx & 2047;
    const float* base = ml + ((size_t)b * 32) * 2 * 2048 + i;
    float M = -3.0e38f;
#pragma unroll 8
    for (int t = 0; t < 32; ++t)
        M = fmaxf(M, base[(size_t)t * 4096]);
    float L = 0.f;
    float* cb = corr + (size_t)b * 32 * 2048 + i;
#pragma unroll 8
    for (int t = 0; t < 32; ++t) {
        const float c = __expf(base[(size_t)t * 4096] - M);
        L += c * base[(size_t)t * 4096 + 2048];
        cb[(size_t)t * 2048] = c;
    }
    linv[idx] = 1.0f / L;
}

// ---------------------------------------------------------------------------
extern "C" void kernel_launch(void* const* d_in, const int* in_sizes, int n_in,
                              void* d_out, int out_size, void* d_ws, size_t ws_size,
                              hipStream_t stream)
{
    (void)in_sizes; (void)n_in; (void)out_size; (void)ws_size;
    const float* x  = (const float*)d_in[0];
    const float* Wq = (const float*)d_in[1];
    const float* gq = (const float*)d_in[2];
    const float* bq = (const float*)d_in[3];
    const float* mq = (const float*)d_in[4];
    const float* vq = (const float*)d_in[5];
    const float* Wk = (const float*)d_in[6];
    const float* gk = (const float*)d_in[7];
    const float* bk = (const float*)d_in[8];
    const float* mk = (const float*)d_in[9];
    const float* vk = (const float*)d_in[10];
    const float* Wv = (const float*)d_in[11];
    const float* gv = (const float*)d_in[12];
    const float* bv = (const float*)d_in[13];
    const float* mv = (const float*)d_in[14];
    const float* vv = (const float*)d_in[15];
    float* out = (float*)d_out;

    const size_t MiB = 1048576;
    char* ws = (char*)d_ws;
    // stacked W: [Wq; Wk; Wv] contiguous 1536x512 fp16
    unsigned short* Wst = (unsigned short*)(ws);
    unsigned short* Wqh = Wst;
    unsigned short* Wkh = Wst + 512 * 512;
    unsigned short* Wvh = Wst + 1024 * 512;
    unsigned short* vbf  = (unsigned short*)(ws + 2 * MiB);   // 16 MiB (d,j)
    unsigned short* qkTh = (unsigned short*)(ws + 18 * MiB);  // 32 MiB (n,[q|k])
    unsigned short* xTh  = (unsigned short*)(ws + 50 * MiB);  // 16 MiB (n,c)
    unsigned short* pbuf = (unsigned short*)(ws + 66 * MiB);  // 64 MiB fp16 p
    float* mlbuf = (float*)(ws + 130 * MiB);                  // 4 MiB stats
    float* corr  = (float*)(ws + 134 * MiB);                  // 2 MiB
    float* linv  = (float*)(ws + 136 * MiB);                  // 64 KiB
    float* sg = (float*)(ws + 136 * MiB + 65536);             // 6 KiB each
    float* sb = sg + 1536;
    float* sm = sb + 1536;
    float* sv = sm + 1536;

    const long BS = (long)N_ * C_;              // 1M elems per batch
    const long QKS = (long)N_ * 1024;           // stacked qk per batch

    // --- conversions + param concat ---
    split_x_kernel<<<dim3(N_ / 64, C_ / 64, B_), 256, 0, stream>>>(x, xTh);
    split_w_kernel<<<dim3(256), 256, 0, stream>>>(Wq, Wqh);
    split_w_kernel<<<dim3(256), 256, 0, stream>>>(Wk, Wkh);
    split_w_kernel<<<dim3(256), 256, 0, stream>>>(Wv, Wvh);
    param_concat_kernel<<<dim3(1), 512, 0, stream>>>(
        gq, bq, mq, vq, gk, bk, mk, vk, gv, bv, mv, vv, sg, sb, sm, sv);

    // --- stacked q/k/v projection: M=1536 ([Wq|Wk|Wv]), grid 8*8*6 ---
    qk256<EPI_PROJT><<<dim3(384), 512, 0, stream>>>(
        Wst, xTh, 512, 512, 512, 0, BS, QKS, BS, qkTh, vbf,
        nullptr, sg, sb, sm, sv);

    // --- logits -> p_local fp16 + per-tile stats (256², counted vmcnt) ---
    qk256<EPI_QK><<<dim3(512), 512, 0, stream>>>(
        qkTh, qkTh + 512, 512, 1024, 1024, QKS, QKS, (long)N_ * N_, 0,
        pbuf, nullptr, mlbuf, nullptr, nullptr, nullptr, nullptr);

    // --- combine stats -> corr, linv ---
    ml_combine_kernel<<<dim3(B_ * N_ / 256), 256, 0, stream>>>(
        mlbuf, corr, linv);

    // --- PV (256x128, tri-buffer counted vmcnt, corr-scaled, /l epilogue) ---
    pv256<<<dim3(256), 512, 0, stream>>>(
        pbuf, vbf, 2048, 2048, 2048, (long)N_ * N_, BS, BS, out, corr, linv);
}